// Round 16
// baseline (145.537 us; speedup 1.0000x reference)
//
#include <hip/hip_runtime.h>
#include <hip/hip_bf16.h>

// RotarySelfAttention: B=1 T=4096 C=1024 NH=16 NKV=4 HD=64 WIN=1024
// f2b(all) -> QKV GEMM with FUSED RMSNorm+RoPE epilogue -> flash attention
// (2-barrier staging amortized over 4 tiles/step, MFMA row-sum) -> out GEMM.

#define WIN_SZ 1024

typedef __attribute__((ext_vector_type(8))) short short8;
typedef __attribute__((ext_vector_type(8))) unsigned short ushort8;
typedef __attribute__((ext_vector_type(4))) float f32x4;
typedef __attribute__((ext_vector_type(16))) float f32x16;

#define GLOAD_LDS16(g, s)                                              \
  __builtin_amdgcn_global_load_lds(                                    \
      (const __attribute__((address_space(1))) unsigned int*)(g),      \
      (__attribute__((address_space(3))) unsigned int*)(s), 16, 0, 0)

__device__ __forceinline__ unsigned short f2bf(float f) {
  union { float f; unsigned u; } v; v.f = f;
  unsigned r = v.u + 0x7fffu + ((v.u >> 16) & 1u);
  return (unsigned short)(r >> 16);
}

__device__ __forceinline__ unsigned pk2bf(float lo, float hi) {
  __hip_bfloat162 h = __float22bfloat162_rn(make_float2(lo, hi));
  union { __hip_bfloat162 h; unsigned u; } c; c.h = h; return c.u;
}

__device__ __forceinline__ short8 frag4(unsigned w0, unsigned w1, unsigned w2, unsigned w3) {
  union { unsigned u[4]; short8 s; } x;
  x.u[0] = w0; x.u[1] = w1; x.u[2] = w2; x.u[3] = w3; return x.s;
}

// ---------------- fused fp32 -> bf16 convert for x, wq, wk, wv, wo ----------------
__global__ __launch_bounds__(256) void k_f2b_all(const float* __restrict__ x,
                                                 const float* __restrict__ wq,
                                                 const float* __restrict__ wk,
                                                 const float* __restrict__ wv,
                                                 const float* __restrict__ wo,
                                                 unsigned short* __restrict__ xb,
                                                 unsigned short* __restrict__ wqkvb,
                                                 unsigned short* __restrict__ wob) {
  int q = blockIdx.x * 256 + threadIdx.x;
  const float* src;
  unsigned short* dst;
  int off;
  if (q < 1048576) { src = x; dst = xb; off = q; }
  else if (q < 1310720) { src = wq; dst = wqkvb; off = q - 1048576; }
  else if (q < 1376256) { src = wk; dst = wqkvb + 1024 * 1024; off = q - 1310720; }
  else if (q < 1441792) { src = wv; dst = wqkvb + 1280 * 1024; off = q - 1376256; }
  else { src = wo; dst = wob; off = q - 1441792; }
  float4 v = ((const float4*)src)[off];
  ushort4 o;
  o.x = f2bf(v.x); o.y = f2bf(v.y); o.z = f2bf(v.z); o.w = f2bf(v.w);
  ((ushort4*)dst)[off] = o;
}

// ---------------- QKV GEMM + fused RMSNorm/RoPE epilogue (unchanged) ----------------
__global__ __launch_bounds__(256) void k_gemm_qkv(const unsigned short* __restrict__ A,
                                                  const unsigned short* __restrict__ B,
                                                  const float* __restrict__ qw,
                                                  const float* __restrict__ kw,
                                                  const float* __restrict__ fc,
                                                  const float* __restrict__ fs,
                                                  unsigned short* __restrict__ Qb,
                                                  unsigned short* __restrict__ Kb,
                                                  unsigned short* __restrict__ Vtg) {
  const int K = 1024;
  __shared__ unsigned short As[2][128 * 64];
  __shared__ unsigned short Bs[2][64 * 64];
  const int id = blockIdx.x;
  const int chunk = gridDim.x >> 3;
  const int swz = (id & 7) * chunk + (id >> 3);
  const int n_idx = swz % 24, m_idx = swz / 24;
  const int m0 = m_idx * 128, n0 = n_idx * 64;

  const int tid = threadIdx.x;
  const int w = tid >> 6, l = tid & 63;
  const int wr = w >> 1, wc = w & 1;
  const int r = l & 15, g = l >> 4;
  const int lr = l >> 3, lc = l & 7;
  const int srowb = w * 32, browb = w * 16;

  f32x4 acc[4][2];
#pragma unroll
  for (int i = 0; i < 4; i++)
#pragma unroll
    for (int j = 0; j < 2; j++) acc[i][j] = {0.f, 0.f, 0.f, 0.f};

  const unsigned short* Ag = A + (size_t)(m0 + srowb + lr) * K + lc * 8;
  const unsigned short* Bg = B + (size_t)(n0 + browb + lr) * K + lc * 8;

  auto stage = [&](int buf, int k0) {
#pragma unroll
    for (int it = 0; it < 4; it++)
      GLOAD_LDS16(Ag + (size_t)(it * 8) * K + k0, &As[buf][(srowb + it * 8) * 64]);
#pragma unroll
    for (int it = 0; it < 2; it++)
      GLOAD_LDS16(Bg + (size_t)(it * 8) * K + k0, &Bs[buf][(browb + it * 8) * 64]);
  };

  stage(0, 0);
  __syncthreads();
  int cur = 0;
  const int NT = K >> 6;
  for (int t = 0; t < NT; ++t) {
    if (t + 1 < NT) stage(cur ^ 1, (t + 1) << 6);
    const char* Ab = (const char*)As[cur];
    const char* Bb = (const char*)Bs[cur];
#pragma unroll
    for (int kk = 0; kk < 2; kk++) {
      short8 af[4], bfr[2];
#pragma unroll
      for (int mi = 0; mi < 4; mi++)
        af[mi] = *(const short8*)(Ab + (wr * 64 + mi * 16 + r) * 128 + kk * 64 + g * 16);
#pragma unroll
      for (int nj = 0; nj < 2; nj++)
        bfr[nj] = *(const short8*)(Bb + (wc * 32 + nj * 16 + r) * 128 + kk * 64 + g * 16);
#pragma unroll
      for (int mi = 0; mi < 4; mi++)
#pragma unroll
        for (int nj = 0; nj < 2; nj++)
          acc[mi][nj] = __builtin_amdgcn_mfma_f32_16x16x32_bf16(af[mi], bfr[nj], acc[mi][nj], 0, 0, 0);
    }
    __syncthreads();
    cur ^= 1;
  }

  const int u = n0 >> 6;
  if (u < 20) {
    float* ssb = (float*)As;  // [128][2]
    f32x4 sv[4];
#pragma unroll
    for (int mi = 0; mi < 4; mi++) {
      f32x4 s;
#pragma unroll
      for (int e = 0; e < 4; e++)
        s[e] = acc[mi][0][e] * acc[mi][0][e] + acc[mi][1][e] * acc[mi][1][e];
#pragma unroll
      for (int off = 1; off < 16; off <<= 1)
#pragma unroll
        for (int e = 0; e < 4; e++) s[e] += __shfl_xor(s[e], off);
      sv[mi] = s;
    }
    if (r == 0) {
#pragma unroll
      for (int mi = 0; mi < 4; mi++)
#pragma unroll
        for (int e = 0; e < 4; e++)
          ssb[(wr * 64 + mi * 16 + g * 4 + e) * 2 + wc] = sv[mi][e];
    }
    __syncthreads();
    const float escale = (u < 16) ? 0.1803368801111204f : 1.0f;
    const float* wgt = (u < 16) ? qw : kw;
#pragma unroll
    for (int mi = 0; mi < 4; mi++) {
      const int rl0 = wr * 64 + mi * 16 + g * 4;
      const int row0 = m0 + rl0;
#pragma unroll
      for (int e = 0; e < 4; e++) {
        const int row = row0 + e;
        float ss = ssb[(rl0 + e) * 2] + ssb[(rl0 + e) * 2 + 1];
        float rms = rsqrtf(ss * (1.0f / 64.0f) + 1e-5f);
#pragma unroll
        for (int nj = 0; nj < 2; nj++) {
          const int cl = wc * 32 + nj * 16 + r;
          float vn = acc[mi][nj][e] * rms * wgt[cl];
          float c = fc[row * 32 + (cl >> 1)];
          float s = fs[row * 32 + (cl >> 1)];
          float pvn = __shfl_xor(vn, 1);
          float outv = (cl & 1) ? (pvn * s + vn * c) : (vn * c - pvn * s);
          unsigned short ob = f2bf(outv * escale);
          if (u < 16) Qb[(size_t)row * 1024 + n0 + cl] = ob;
          else Kb[(size_t)row * 256 + (n0 - 1024) + cl] = ob;
        }
      }
    }
  } else {
#pragma unroll
    for (int mi = 0; mi < 4; mi++) {
      const int row0 = m0 + wr * 64 + mi * 16 + g * 4;
#pragma unroll
      for (int nj = 0; nj < 2; nj++) {
        const int d = (n0 - 1280) + wc * 32 + nj * 16 + r;
        ushort4 ov;
        ov.x = f2bf(acc[mi][nj][0]);
        ov.y = f2bf(acc[mi][nj][1]);
        ov.z = f2bf(acc[mi][nj][2]);
        ov.w = f2bf(acc[mi][nj][3]);
        *(ushort4*)(Vtg + (size_t)d * 4096 + row0) = ov;
      }
    }
  }
}

// ---------------- out GEMM: 128x64 dbuf, f32 out (unchanged) ----------------
__global__ __launch_bounds__(256) void k_gemm_out(const unsigned short* __restrict__ A,
                                                  const unsigned short* __restrict__ B,
                                                  float* __restrict__ C) {
  const int K = 1024, N = 1024;
  __shared__ unsigned short As[2][128 * 64];
  __shared__ unsigned short Bs[2][64 * 64];
  const int id = blockIdx.x;
  const int chunk = gridDim.x >> 3;
  const int swz = (id & 7) * chunk + (id >> 3);
  const int n_idx = swz % 16, m_idx = swz / 16;
  const int m0 = m_idx * 128, n0 = n_idx * 64;

  const int tid = threadIdx.x;
  const int w = tid >> 6, l = tid & 63;
  const int wr = w >> 1, wc = w & 1;
  const int r = l & 15, g = l >> 4;
  const int lr = l >> 3, lc = l & 7;
  const int srowb = w * 32, browb = w * 16;

  f32x4 acc[4][2];
#pragma unroll
  for (int i = 0; i < 4; i++)
#pragma unroll
    for (int j = 0; j < 2; j++) acc[i][j] = {0.f, 0.f, 0.f, 0.f};

  const unsigned short* Ag = A + (size_t)(m0 + srowb + lr) * K + lc * 8;
  const unsigned short* Bg = B + (size_t)(n0 + browb + lr) * K + lc * 8;

  auto stage = [&](int buf, int k0) {
#pragma unroll
    for (int it = 0; it < 4; it++)
      GLOAD_LDS16(Ag + (size_t)(it * 8) * K + k0, &As[buf][(srowb + it * 8) * 64]);
#pragma unroll
    for (int it = 0; it < 2; it++)
      GLOAD_LDS16(Bg + (size_t)(it * 8) * K + k0, &Bs[buf][(browb + it * 8) * 64]);
  };

  stage(0, 0);
  __syncthreads();
  int cur = 0;
  const int NT = K >> 6;
  for (int t = 0; t < NT; ++t) {
    if (t + 1 < NT) stage(cur ^ 1, (t + 1) << 6);
    const char* Ab = (const char*)As[cur];
    const char* Bb = (const char*)Bs[cur];
#pragma unroll
    for (int kk = 0; kk < 2; kk++) {
      short8 af[4], bfr[2];
#pragma unroll
      for (int mi = 0; mi < 4; mi++)
        af[mi] = *(const short8*)(Ab + (wr * 64 + mi * 16 + r) * 128 + kk * 64 + g * 16);
#pragma unroll
      for (int nj = 0; nj < 2; nj++)
        bfr[nj] = *(const short8*)(Bb + (wc * 32 + nj * 16 + r) * 128 + kk * 64 + g * 16);
#pragma unroll
      for (int mi = 0; mi < 4; mi++)
#pragma unroll
        for (int nj = 0; nj < 2; nj++)
          acc[mi][nj] = __builtin_amdgcn_mfma_f32_16x16x32_bf16(af[mi], bfr[nj], acc[mi][nj], 0, 0, 0);
    }
    __syncthreads();
    cur ^= 1;
  }

#pragma unroll
  for (int mi = 0; mi < 4; mi++)
#pragma unroll
    for (int nj = 0; nj < 2; nj++) {
      int row = m0 + wr * 64 + mi * 16 + g * 4;
      int col = n0 + wc * 32 + nj * 16 + r;
#pragma unroll
      for (int e = 0; e < 4; e++)
        C[(size_t)(row + e) * N + col] = acc[mi][nj][e];
    }
}

// ---------------- flash attention: 4 tiles per 2-barrier step ----------------
// Grid 512 (complementary remap). Block 512 thr = 8 waves = 4 heads x 2 j-halves.
// Staging: 8 x 8KB buffers = {2 tile-pairs} x {2 halves} x {K,V}; 64 thr/buffer,
// one 128B j-row each. Per step each half computes up to 2 sequential tiles
// (ascending j -> online softmax unchanged). lsum via mfma(ones, P).
__global__ __launch_bounds__(512, 4) void k_attn10(const unsigned short* __restrict__ Qb,
                                                   const unsigned short* __restrict__ Kb,
                                                   const unsigned short* __restrict__ Vtg,
                                                   unsigned short* __restrict__ Yb) {
  __shared__ char smem[8 * 8192 + 1024];
  char* stage = smem;
  float* Obuf = (float*)smem;
  float* ml = (float*)(smem + 65536);

  const int id = blockIdx.x;
  const int cupair = id & 255, sel = id >> 8;
  int qi = cupair >> 1;
  if (sel) qi = 127 - qi;
  const int hk = (cupair & 1) * 2 + sel;
  const int q0 = qi * 32;

  const int tid = threadIdx.x, w = tid >> 6, l = tid & 63;
  const int hh = w & 3, half = w >> 2;
  const int h = hk * 4 + hh;
  const int l31 = l & 31, hi = l >> 5, l15 = l & 15;
  const int qrow = q0 + l31;

  int jlo = q0 - (WIN_SZ - 1);
  if (jlo < 0) jlo = 0;
  jlo &= ~63;
  const int jlast = ((q0 + 31) >> 6) << 6;
  const int nt = ((jlast - jlo) >> 6) + 1;
  const int nh0 = (nt + 1) >> 1;
  const int S = (nh0 + 1) >> 1;

  // staging roles: sb bit2 = half(q), bit1 = pair(p), bit0 = isV
  const int sb = tid >> 6;
  const int sq = sb >> 2;
  const int sp = (sb >> 1) & 1;
  const bool isV = sb & 1;
  const int srow = tid & 63;
  const int sbase = sb * 8192 + (srow & 31) * 256;
  const int srx = (srow & 15) << 4;
  const int srh = (srow >> 5) * 128;
  const unsigned short* gK = Kb + (size_t)srow * 256 + hk * 64;
  const unsigned short* gV = Vtg + (size_t)(hk * 64 + srow) * 4096;

  short8 qf[4];
#pragma unroll
  for (int ks = 0; ks < 4; ks++)
    qf[ks] = *(const short8*)(Qb + (size_t)qrow * 1024 + h * 64 + ks * 16 + hi * 8);

  const short8 ones = frag4(0x3F803F80u, 0x3F803F80u, 0x3F803F80u, 0x3F803F80u);

  f32x16 accO0, accO1;
#pragma unroll
  for (int i = 0; i < 16; i++) { accO0[i] = 0.f; accO1[i] = 0.f; }
  float m = -1e30f, lsum = 0.f;

  ushort8 pre[8];
  auto prefetch = [&](int s) {
    int t = (sq ? nh0 : 0) + 2 * s + sp;
    int lim = sq ? nt : nh0;
    int jt = (t < lim) ? (jlo + (t << 6)) : jlo;
    if (!isV) {
      const unsigned short* g = gK + (size_t)jt * 256;
#pragma unroll
      for (int e = 0; e < 8; e++) pre[e] = *(const ushort8*)(g + e * 8);
    } else {
      const unsigned short* g = gV + jt;
#pragma unroll
      for (int e = 0; e < 8; e++) pre[e] = *(const ushort8*)(g + e * 8);
    }
  };
  prefetch(0);

  const int tbase = half ? nh0 : 0;
  const int tlim = half ? nt : nh0;

  for (int s = 0; s < S; ++s) {
    __syncthreads();
#pragma unroll
    for (int e = 0; e < 8; e++) {
      int dst = sbase + ((srh + e * 16) ^ srx);
      *(ushort8*)(stage + dst) = pre[e];
    }
    __syncthreads();
    if (s + 1 < S) prefetch(s + 1);

#pragma unroll
    for (int p = 0; p < 2; ++p) {
      const int myt = tbase + 2 * s + p;
      if (myt < tlim) {
        const int jt = jlo + (myt << 6);
        const int kbase = (half * 4 + p * 2) * 8192;
        const int vbase = kbase + 8192;

        f32x16 st0, st1;
#pragma unroll
        for (int i = 0; i < 16; i++) { st0[i] = 0.f; st1[i] = 0.f; }
        __builtin_amdgcn_s_setprio(1);
#pragma unroll
        for (int ks = 0; ks < 4; ks++) {
          int colb = ks * 32 + hi * 16;
          short8 kf0 = *(const short8*)(stage + kbase + l31 * 256 + (colb ^ (l15 << 4)));
          st0 = __builtin_amdgcn_mfma_f32_32x32x16_bf16(kf0, qf[ks], st0, 0, 0, 0);
          short8 kf1 = *(const short8*)(stage + kbase + l31 * 256 + ((128 + colb) ^ (l15 << 4)));
          st1 = __builtin_amdgcn_mfma_f32_32x32x16_bf16(kf1, qf[ks], st1, 0, 0, 0);
        }
        __builtin_amdgcn_s_setprio(0);

        if (jt + 63 > q0 || (q0 + 31) - jt >= WIN_SZ) {
          const int jb = jt + hi * 4;
#pragma unroll
          for (int rg = 0; rg < 16; rg++) {
            int j0 = jb + (rg & 3) + 8 * (rg >> 2);
            if (!((j0 <= qrow) && (qrow - j0 < WIN_SZ))) st0[rg] = -3.0e38f;
            int j1 = j0 + 32;
            if (!((j1 <= qrow) && (qrow - j1 < WIN_SZ))) st1[rg] = -3.0e38f;
          }
        }

        float mx = st0[0];
#pragma unroll
        for (int rg = 1; rg < 16; rg++) mx = fmaxf(mx, st0[rg]);
#pragma unroll
        for (int rg = 0; rg < 16; rg++) mx = fmaxf(mx, st1[rg]);
        mx = fmaxf(mx, __shfl_xor(mx, 32));
        if (!__all(mx <= m + 8.0f)) {
          float mnew = fmaxf(m, mx);
          float alpha = exp2f(m - mnew);
#pragma unroll
          for (int rg = 0; rg < 16; rg++) { accO0[rg] *= alpha; accO1[rg] *= alpha; }
          lsum *= alpha;
          m = mnew;
        }
#pragma unroll
        for (int rg = 0; rg < 16; rg++) st0[rg] = exp2f(st0[rg] - m);
#pragma unroll
        for (int rg = 0; rg < 16; rg++) st1[rg] = exp2f(st1[rg] - m);

        unsigned pd0[2][4], pd1[2][4];
#pragma unroll
        for (int b = 0; b < 4; b++) {
          pd0[0][b] = pk2bf(st0[4 * b], st0[4 * b + 1]);
          pd1[0][b] = pk2bf(st0[4 * b + 2], st0[4 * b + 3]);
          pd0[1][b] = pk2bf(st1[4 * b], st1[4 * b + 1]);
          pd1[1][b] = pk2bf(st1[4 * b + 2], st1[4 * b + 3]);
        }

        f32x16 accL;
#pragma unroll
        for (int i = 0; i < 16; i++) accL[i] = 0.f;

        __builtin_amdgcn_s_setprio(1);
#pragma unroll
        for (int jj = 0; jj < 2; jj++) {
#pragma unroll
          for (int ks2 = 0; ks2 < 2; ks2++) {
            unsigned a0 = pd0[jj][2 * ks2], a1 = pd0[jj][2 * ks2 + 1];
            unsigned b0 = pd1[jj][2 * ks2], b1 = pd1[jj][2 * ks2 + 1];
            unsigned a0x = __shfl_xor(a0, 32), a1x = __shfl_xor(a1, 32);
            unsigned b0x = __shfl_xor(b0, 32), b1x = __shfl_xor(b1, 32);
            unsigned w0 = hi ? a1x : a0;
            unsigned w1 = hi ? b1x : b0;
            unsigned w2 = hi ? a1 : a0x;
            unsigned w3 = hi ? b1 : b0x;
            short8 pf = frag4(w0, w1, w2, w3);
            int colb2 = jj * 64 + ks2 * 32 + hi * 16;
            short8 vf0 = *(const short8*)(stage + vbase + l31 * 256 + (colb2 ^ (l15 << 4)));
            accO0 = __builtin_amdgcn_mfma_f32_32x32x16_bf16(vf0, pf, accO0, 0, 0, 0);
            short8 vf1 = *(const short8*)(stage + vbase + l31 * 256 + ((128 + colb2) ^ (l15 << 4)));
            accO1 = __builtin_amdgcn_mfma_f32_32x32x16_bf16(vf1, pf, accO1, 0, 0, 0);
            accL = __builtin_amdgcn_mfma_f32_32x32x16_bf16(ones, pf, accL, 0, 0, 0);
          }
        }
        __builtin_amdgcn_s_setprio(0);
        lsum += accL[0];
      }
    }
  }

  __syncthreads();
  if (half == 1) {
#pragma unroll
    for (int dd = 0; dd < 2; dd++) {
      const f32x16& a = dd ? accO1 : accO0;
#pragma unroll
      for (int rg = 0; rg < 16; rg++) {
        int d = dd * 32 + 8 * (rg >> 2) + 4 * hi + (rg & 3);
        Obuf[(hh * 64 + d) * 32 + l31] = a[rg];
      }
    }
    if (!hi) { ml[(hh * 2 + 0) * 32 + l31] = m; ml[(hh * 2 + 1) * 32 + l31] = lsum; }
  }
  __syncthreads();
  if (half == 0) {
    float m1 = ml[(hh * 2 + 0) * 32 + l31];
    float l1 = ml[(hh * 2 + 1) * 32 + l31];
    float ms = fmaxf(m, m1);
    float a0 = exp2f(m - ms), a1 = exp2f(m1 - ms);
    float inv = 1.0f / (lsum * a0 + l1 * a1);
    a0 *= inv; a1 *= inv;
#pragma unroll
    for (int dd = 0; dd < 2; dd++) {
      const f32x16& a = dd ? accO1 : accO0;
#pragma unroll
      for (int b = 0; b < 4; b++) {
        float o[4];
#pragma unroll
        for (int e = 0; e < 4; e++) {
          int d = dd * 32 + 8 * b + 4 * hi + e;
          o[e] = a[4 * b + e] * a0 + Obuf[(hh * 64 + d) * 32 + l31] * a1;
        }
        union { unsigned uu[2]; ushort4 v; } ov;
        ov.uu[0] = pk2bf(o[0], o[1]);
        ov.uu[1] = pk2bf(o[2], o[3]);
        *(ushort4*)(Yb + (size_t)qrow * 1024 + h * 64 + dd * 32 + b * 8 + hi * 4) = ov.v;
      }
    }
  }
}

extern "C" void kernel_launch(void* const* d_in, const int* in_sizes, int n_in,
                              void* d_out, int out_size, void* d_ws, size_t ws_size,
                              hipStream_t stream) {
  const float* x = (const float*)d_in[0];
  const float* wq = (const float*)d_in[1];
  const float* wk = (const float*)d_in[2];
  const float* wv = (const float*)d_in[3];
  const float* wo = (const float*)d_in[4];
  const float* qw = (const float*)d_in[5];
  const float* kw = (const float*)d_in[6];
  const float* fc = (const float*)d_in[7];
  const float* fs = (const float*)d_in[8];
  float* out = (float*)d_out;

  char* p = (char*)d_ws;
  auto alloc = [&](size_t b) {
    char* q = p;
    p += (b + 255) & ~(size_t)255;
    return q;
  };
  unsigned short* xb = (unsigned short*)alloc((size_t)4096 * 1024 * 2);
  unsigned short* wqkvb = (unsigned short*)alloc((size_t)1536 * 1024 * 2);
  unsigned short* wob = (unsigned short*)alloc((size_t)1024 * 1024 * 2);
  unsigned short* Qb = (unsigned short*)alloc((size_t)4096 * 1024 * 2);
  unsigned short* Kb = (unsigned short*)alloc((size_t)4096 * 256 * 2);
  unsigned short* Vtg = (unsigned short*)alloc((size_t)256 * 4096 * 2);
  unsigned short* Yb = (unsigned short*)alloc((size_t)4096 * 1024 * 2);

  k_f2b_all<<<6656, 256, 0, stream>>>(x, wq, wk, wv, wo, xb, wqkvb, wob);
  k_gemm_qkv<<<768, 256, 0, stream>>>(xb, wqkvb, qw, kw, fc, fs, Qb, Kb, Vtg);
  k_attn10<<<512, 512, 0, stream>>>(Qb, Kb, Vtg, Yb);
  k_gemm_out<<<512, 256, 0, stream>>>(Yb, wob, out);
}

// Round 17
// 108.690 us; speedup vs baseline: 1.3390x; 1.3390x over previous
//
#include <hip/hip_runtime.h>
#include <hip/hip_bf16.h>

// RotarySelfAttention: B=1 T=4096 C=1024 NH=16 NKV=4 HD=64 WIN=1024
// Best-known configuration (R15): f2b(all) -> QKV GEMM with FUSED RMSNorm+RoPE
// epilogue -> flash attention (R8 2-barrier staging, complementary remap,
// MFMA row-sum) -> out GEMM.

#define WIN_SZ 1024

typedef __attribute__((ext_vector_type(8))) short short8;
typedef __attribute__((ext_vector_type(8))) unsigned short ushort8;
typedef __attribute__((ext_vector_type(4))) float f32x4;
typedef __attribute__((ext_vector_type(16))) float f32x16;

#define GLOAD_LDS16(g, s)                                              \
  __builtin_amdgcn_global_load_lds(                                    \
      (const __attribute__((address_space(1))) unsigned int*)(g),      \
      (__attribute__((address_space(3))) unsigned int*)(s), 16, 0, 0)

__device__ __forceinline__ unsigned short f2bf(float f) {
  union { float f; unsigned u; } v; v.f = f;
  unsigned r = v.u + 0x7fffu + ((v.u >> 16) & 1u);
  return (unsigned short)(r >> 16);
}

__device__ __forceinline__ unsigned pk2bf(float lo, float hi) {
  __hip_bfloat162 h = __float22bfloat162_rn(make_float2(lo, hi));
  union { __hip_bfloat162 h; unsigned u; } c; c.h = h; return c.u;
}

__device__ __forceinline__ short8 frag4(unsigned w0, unsigned w1, unsigned w2, unsigned w3) {
  union { unsigned u[4]; short8 s; } x;
  x.u[0] = w0; x.u[1] = w1; x.u[2] = w2; x.u[3] = w3; return x.s;
}

// ---------------- fused fp32 -> bf16 convert for x, wq, wk, wv, wo ----------------
__global__ __launch_bounds__(256) void k_f2b_all(const float* __restrict__ x,
                                                 const float* __restrict__ wq,
                                                 const float* __restrict__ wk,
                                                 const float* __restrict__ wv,
                                                 const float* __restrict__ wo,
                                                 unsigned short* __restrict__ xb,
                                                 unsigned short* __restrict__ wqkvb,
                                                 unsigned short* __restrict__ wob) {
  int q = blockIdx.x * 256 + threadIdx.x;
  const float* src;
  unsigned short* dst;
  int off;
  if (q < 1048576) { src = x; dst = xb; off = q; }
  else if (q < 1310720) { src = wq; dst = wqkvb; off = q - 1048576; }
  else if (q < 1376256) { src = wk; dst = wqkvb + 1024 * 1024; off = q - 1310720; }
  else if (q < 1441792) { src = wv; dst = wqkvb + 1280 * 1024; off = q - 1376256; }
  else { src = wo; dst = wob; off = q - 1441792; }
  float4 v = ((const float4*)src)[off];
  ushort4 o;
  o.x = f2bf(v.x); o.y = f2bf(v.y); o.z = f2bf(v.z); o.w = f2bf(v.w);
  ((ushort4*)dst)[off] = o;
}

// ---------------- QKV GEMM + fused RMSNorm/RoPE epilogue ----------------
__global__ __launch_bounds__(256) void k_gemm_qkv(const unsigned short* __restrict__ A,
                                                  const unsigned short* __restrict__ B,
                                                  const float* __restrict__ qw,
                                                  const float* __restrict__ kw,
                                                  const float* __restrict__ fc,
                                                  const float* __restrict__ fs,
                                                  unsigned short* __restrict__ Qb,
                                                  unsigned short* __restrict__ Kb,
                                                  unsigned short* __restrict__ Vtg) {
  const int K = 1024;
  __shared__ unsigned short As[2][128 * 64];
  __shared__ unsigned short Bs[2][64 * 64];
  const int id = blockIdx.x;
  const int chunk = gridDim.x >> 3;
  const int swz = (id & 7) * chunk + (id >> 3);
  const int n_idx = swz % 24, m_idx = swz / 24;
  const int m0 = m_idx * 128, n0 = n_idx * 64;

  const int tid = threadIdx.x;
  const int w = tid >> 6, l = tid & 63;
  const int wr = w >> 1, wc = w & 1;
  const int r = l & 15, g = l >> 4;
  const int lr = l >> 3, lc = l & 7;
  const int srowb = w * 32, browb = w * 16;

  f32x4 acc[4][2];
#pragma unroll
  for (int i = 0; i < 4; i++)
#pragma unroll
    for (int j = 0; j < 2; j++) acc[i][j] = {0.f, 0.f, 0.f, 0.f};

  const unsigned short* Ag = A + (size_t)(m0 + srowb + lr) * K + lc * 8;
  const unsigned short* Bg = B + (size_t)(n0 + browb + lr) * K + lc * 8;

  auto stage = [&](int buf, int k0) {
#pragma unroll
    for (int it = 0; it < 4; it++)
      GLOAD_LDS16(Ag + (size_t)(it * 8) * K + k0, &As[buf][(srowb + it * 8) * 64]);
#pragma unroll
    for (int it = 0; it < 2; it++)
      GLOAD_LDS16(Bg + (size_t)(it * 8) * K + k0, &Bs[buf][(browb + it * 8) * 64]);
  };

  stage(0, 0);
  __syncthreads();
  int cur = 0;
  const int NT = K >> 6;
  for (int t = 0; t < NT; ++t) {
    if (t + 1 < NT) stage(cur ^ 1, (t + 1) << 6);
    const char* Ab = (const char*)As[cur];
    const char* Bb = (const char*)Bs[cur];
#pragma unroll
    for (int kk = 0; kk < 2; kk++) {
      short8 af[4], bfr[2];
#pragma unroll
      for (int mi = 0; mi < 4; mi++)
        af[mi] = *(const short8*)(Ab + (wr * 64 + mi * 16 + r) * 128 + kk * 64 + g * 16);
#pragma unroll
      for (int nj = 0; nj < 2; nj++)
        bfr[nj] = *(const short8*)(Bb + (wc * 32 + nj * 16 + r) * 128 + kk * 64 + g * 16);
#pragma unroll
      for (int mi = 0; mi < 4; mi++)
#pragma unroll
        for (int nj = 0; nj < 2; nj++)
          acc[mi][nj] = __builtin_amdgcn_mfma_f32_16x16x32_bf16(af[mi], bfr[nj], acc[mi][nj], 0, 0, 0);
    }
    __syncthreads();
    cur ^= 1;
  }

  const int u = n0 >> 6;
  if (u < 20) {
    float* ssb = (float*)As;  // [128][2]
    f32x4 sv[4];
#pragma unroll
    for (int mi = 0; mi < 4; mi++) {
      f32x4 s;
#pragma unroll
      for (int e = 0; e < 4; e++)
        s[e] = acc[mi][0][e] * acc[mi][0][e] + acc[mi][1][e] * acc[mi][1][e];
#pragma unroll
      for (int off = 1; off < 16; off <<= 1)
#pragma unroll
        for (int e = 0; e < 4; e++) s[e] += __shfl_xor(s[e], off);
      sv[mi] = s;
    }
    if (r == 0) {
#pragma unroll
      for (int mi = 0; mi < 4; mi++)
#pragma unroll
        for (int e = 0; e < 4; e++)
          ssb[(wr * 64 + mi * 16 + g * 4 + e) * 2 + wc] = sv[mi][e];
    }
    __syncthreads();
    const float escale = (u < 16) ? 0.1803368801111204f : 1.0f;
    const float* wgt = (u < 16) ? qw : kw;
#pragma unroll
    for (int mi = 0; mi < 4; mi++) {
      const int rl0 = wr * 64 + mi * 16 + g * 4;
      const int row0 = m0 + rl0;
#pragma unroll
      for (int e = 0; e < 4; e++) {
        const int row = row0 + e;
        float ss = ssb[(rl0 + e) * 2] + ssb[(rl0 + e) * 2 + 1];
        float rms = rsqrtf(ss * (1.0f / 64.0f) + 1e-5f);
#pragma unroll
        for (int nj = 0; nj < 2; nj++) {
          const int cl = wc * 32 + nj * 16 + r;
          float vn = acc[mi][nj][e] * rms * wgt[cl];
          float c = fc[row * 32 + (cl >> 1)];
          float s = fs[row * 32 + (cl >> 1)];
          float pvn = __shfl_xor(vn, 1);
          float outv = (cl & 1) ? (pvn * s + vn * c) : (vn * c - pvn * s);
          unsigned short ob = f2bf(outv * escale);
          if (u < 16) Qb[(size_t)row * 1024 + n0 + cl] = ob;
          else Kb[(size_t)row * 256 + (n0 - 1024) + cl] = ob;
        }
      }
    }
  } else {
#pragma unroll
    for (int mi = 0; mi < 4; mi++) {
      const int row0 = m0 + wr * 64 + mi * 16 + g * 4;
#pragma unroll
      for (int nj = 0; nj < 2; nj++) {
        const int d = (n0 - 1280) + wc * 32 + nj * 16 + r;
        ushort4 ov;
        ov.x = f2bf(acc[mi][nj][0]);
        ov.y = f2bf(acc[mi][nj][1]);
        ov.z = f2bf(acc[mi][nj][2]);
        ov.w = f2bf(acc[mi][nj][3]);
        *(ushort4*)(Vtg + (size_t)d * 4096 + row0) = ov;
      }
    }
  }
}

// ---------------- out GEMM: 128x64 dbuf, f32 out ----------------
__global__ __launch_bounds__(256) void k_gemm_out(const unsigned short* __restrict__ A,
                                                  const unsigned short* __restrict__ B,
                                                  float* __restrict__ C) {
  const int K = 1024, N = 1024;
  __shared__ unsigned short As[2][128 * 64];
  __shared__ unsigned short Bs[2][64 * 64];
  const int id = blockIdx.x;
  const int chunk = gridDim.x >> 3;
  const int swz = (id & 7) * chunk + (id >> 3);
  const int n_idx = swz % 16, m_idx = swz / 16;
  const int m0 = m_idx * 128, n0 = n_idx * 64;

  const int tid = threadIdx.x;
  const int w = tid >> 6, l = tid & 63;
  const int wr = w >> 1, wc = w & 1;
  const int r = l & 15, g = l >> 4;
  const int lr = l >> 3, lc = l & 7;
  const int srowb = w * 32, browb = w * 16;

  f32x4 acc[4][2];
#pragma unroll
  for (int i = 0; i < 4; i++)
#pragma unroll
    for (int j = 0; j < 2; j++) acc[i][j] = {0.f, 0.f, 0.f, 0.f};

  const unsigned short* Ag = A + (size_t)(m0 + srowb + lr) * K + lc * 8;
  const unsigned short* Bg = B + (size_t)(n0 + browb + lr) * K + lc * 8;

  auto stage = [&](int buf, int k0) {
#pragma unroll
    for (int it = 0; it < 4; it++)
      GLOAD_LDS16(Ag + (size_t)(it * 8) * K + k0, &As[buf][(srowb + it * 8) * 64]);
#pragma unroll
    for (int it = 0; it < 2; it++)
      GLOAD_LDS16(Bg + (size_t)(it * 8) * K + k0, &Bs[buf][(browb + it * 8) * 64]);
  };

  stage(0, 0);
  __syncthreads();
  int cur = 0;
  const int NT = K >> 6;
  for (int t = 0; t < NT; ++t) {
    if (t + 1 < NT) stage(cur ^ 1, (t + 1) << 6);
    const char* Ab = (const char*)As[cur];
    const char* Bb = (const char*)Bs[cur];
#pragma unroll
    for (int kk = 0; kk < 2; kk++) {
      short8 af[4], bfr[2];
#pragma unroll
      for (int mi = 0; mi < 4; mi++)
        af[mi] = *(const short8*)(Ab + (wr * 64 + mi * 16 + r) * 128 + kk * 64 + g * 16);
#pragma unroll
      for (int nj = 0; nj < 2; nj++)
        bfr[nj] = *(const short8*)(Bb + (wc * 32 + nj * 16 + r) * 128 + kk * 64 + g * 16);
#pragma unroll
      for (int mi = 0; mi < 4; mi++)
#pragma unroll
        for (int nj = 0; nj < 2; nj++)
          acc[mi][nj] = __builtin_amdgcn_mfma_f32_16x16x32_bf16(af[mi], bfr[nj], acc[mi][nj], 0, 0, 0);
    }
    __syncthreads();
    cur ^= 1;
  }

#pragma unroll
  for (int mi = 0; mi < 4; mi++)
#pragma unroll
    for (int nj = 0; nj < 2; nj++) {
      int row = m0 + wr * 64 + mi * 16 + g * 4;
      int col = n0 + wc * 32 + nj * 16 + r;
#pragma unroll
      for (int e = 0; e < 4; e++)
        C[(size_t)(row + e) * N + col] = acc[mi][nj][e];
    }
}

// ---------------- flash attention: R8 structure + MFMA row-sum ----------------
__global__ __launch_bounds__(512, 4) void k_attn9(const unsigned short* __restrict__ Qb,
                                                  const unsigned short* __restrict__ Kb,
                                                  const unsigned short* __restrict__ Vtg,
                                                  unsigned short* __restrict__ Yb) {
  __shared__ char smem[4 * 8192 + 1024];
  char* stage = smem;
  float* Obuf = (float*)smem;
  float* ml = (float*)(smem + 32768);

  const int id = blockIdx.x;
  const int cupair = id & 255, sel = id >> 8;
  int qi = cupair >> 1;
  if (sel) qi = 127 - qi;
  const int hk = (cupair & 1) * 2 + sel;
  const int q0 = qi * 32;

  const int tid = threadIdx.x, w = tid >> 6, l = tid & 63;
  const int hh = w & 3, half = w >> 2;
  const int h = hk * 4 + hh;
  const int l31 = l & 31, hi = l >> 5, l15 = l & 15;
  const int qrow = q0 + l31;

  int jlo = q0 - (WIN_SZ - 1);
  if (jlo < 0) jlo = 0;
  jlo &= ~63;
  const int jlast = ((q0 + 31) >> 6) << 6;
  const int nt = ((jlast - jlo) >> 6) + 1;
  const int nh0 = (nt + 1) >> 1;

  const int sb = tid >> 7;
  const int su = tid & 127;
  const int srow = su >> 1;
  const int sg = (su & 1) * 4;
  const int sbase = sb * 8192 + (srow & 31) * 256;
  const int srx = (srow & 15) << 4;
  const int srh = (srow >> 5) * 128;
  const bool isV = sb & 1;
  const unsigned short* gK = Kb + (size_t)srow * 256 + hk * 64 + sg * 8;
  const unsigned short* gV = Vtg + (size_t)(hk * 64 + srow) * 4096 + sg * 8;

  short8 qf[4];
#pragma unroll
  for (int ks = 0; ks < 4; ks++)
    qf[ks] = *(const short8*)(Qb + (size_t)qrow * 1024 + h * 64 + ks * 16 + hi * 8);

  const short8 ones = frag4(0x3F803F80u, 0x3F803F80u, 0x3F803F80u, 0x3F803F80u);

  f32x16 accO0, accO1;
#pragma unroll
  for (int i = 0; i < 16; i++) { accO0[i] = 0.f; accO1[i] = 0.f; }
  float m = -1e30f, lsum = 0.f;

  ushort8 pre[4];
  auto prefetch = [&](int s) {
    int jt0 = jlo + (s << 6);
    int t1 = nh0 + s;
    int jt1 = (t1 < nt) ? (jlo + (t1 << 6)) : jlo;
    int jt = (sb >= 2) ? jt1 : jt0;
    if (!isV) {
      const unsigned short* g = gK + (size_t)jt * 256;
#pragma unroll
      for (int e = 0; e < 4; e++) pre[e] = *(const ushort8*)(g + e * 8);
    } else {
      const unsigned short* g = gV + jt;
#pragma unroll
      for (int e = 0; e < 4; e++) pre[e] = *(const ushort8*)(g + e * 8);
    }
  };
  prefetch(0);

  const int kbase = half * 16384;
  const int vbase = kbase + 8192;

  for (int s = 0; s < nh0; ++s) {
    __syncthreads();
#pragma unroll
    for (int e = 0; e < 4; e++) {
      int dst = sbase + ((srh + (sg + e) * 16) ^ srx);
      *(ushort8*)(stage + dst) = pre[e];
    }
    __syncthreads();
    if (s + 1 < nh0) prefetch(s + 1);

    const int myt = half ? (nh0 + s) : s;
    if (myt < nt) {
      const int jt = jlo + (myt << 6);

      f32x16 st0, st1;
#pragma unroll
      for (int i = 0; i < 16; i++) { st0[i] = 0.f; st1[i] = 0.f; }
      __builtin_amdgcn_s_setprio(1);
#pragma unroll
      for (int ks = 0; ks < 4; ks++) {
        int colb = ks * 32 + hi * 16;
        short8 kf0 = *(const short8*)(stage + kbase + l31 * 256 + (colb ^ (l15 << 4)));
        st0 = __builtin_amdgcn_mfma_f32_32x32x16_bf16(kf0, qf[ks], st0, 0, 0, 0);
        short8 kf1 = *(const short8*)(stage + kbase + l31 * 256 + ((128 + colb) ^ (l15 << 4)));
        st1 = __builtin_amdgcn_mfma_f32_32x32x16_bf16(kf1, qf[ks], st1, 0, 0, 0);
      }
      __builtin_amdgcn_s_setprio(0);

      if (jt + 63 > q0 || (q0 + 31) - jt >= WIN_SZ) {
        const int jb = jt + hi * 4;
#pragma unroll
        for (int rg = 0; rg < 16; rg++) {
          int j0 = jb + (rg & 3) + 8 * (rg >> 2);
          if (!((j0 <= qrow) && (qrow - j0 < WIN_SZ))) st0[rg] = -3.0e38f;
          int j1 = j0 + 32;
          if (!((j1 <= qrow) && (qrow - j1 < WIN_SZ))) st1[rg] = -3.0e38f;
        }
      }

      float mx = st0[0];
#pragma unroll
      for (int rg = 1; rg < 16; rg++) mx = fmaxf(mx, st0[rg]);
#pragma unroll
      for (int rg = 0; rg < 16; rg++) mx = fmaxf(mx, st1[rg]);
      mx = fmaxf(mx, __shfl_xor(mx, 32));
      if (!__all(mx <= m + 8.0f)) {
        float mnew = fmaxf(m, mx);
        float alpha = exp2f(m - mnew);
#pragma unroll
        for (int rg = 0; rg < 16; rg++) { accO0[rg] *= alpha; accO1[rg] *= alpha; }
        lsum *= alpha;
        m = mnew;
      }
#pragma unroll
      for (int rg = 0; rg < 16; rg++) st0[rg] = exp2f(st0[rg] - m);
#pragma unroll
      for (int rg = 0; rg < 16; rg++) st1[rg] = exp2f(st1[rg] - m);

      unsigned pd0[2][4], pd1[2][4];
#pragma unroll
      for (int b = 0; b < 4; b++) {
        pd0[0][b] = pk2bf(st0[4 * b], st0[4 * b + 1]);
        pd1[0][b] = pk2bf(st0[4 * b + 2], st0[4 * b + 3]);
        pd0[1][b] = pk2bf(st1[4 * b], st1[4 * b + 1]);
        pd1[1][b] = pk2bf(st1[4 * b + 2], st1[4 * b + 3]);
      }

      f32x16 accL;
#pragma unroll
      for (int i = 0; i < 16; i++) accL[i] = 0.f;

      __builtin_amdgcn_s_setprio(1);
#pragma unroll
      for (int jj = 0; jj < 2; jj++) {
#pragma unroll
        for (int ks2 = 0; ks2 < 2; ks2++) {
          unsigned a0 = pd0[jj][2 * ks2], a1 = pd0[jj][2 * ks2 + 1];
          unsigned b0 = pd1[jj][2 * ks2], b1 = pd1[jj][2 * ks2 + 1];
          unsigned a0x = __shfl_xor(a0, 32), a1x = __shfl_xor(a1, 32);
          unsigned b0x = __shfl_xor(b0, 32), b1x = __shfl_xor(b1, 32);
          unsigned w0 = hi ? a1x : a0;
          unsigned w1 = hi ? b1x : b0;
          unsigned w2 = hi ? a1 : a0x;
          unsigned w3 = hi ? b1 : b0x;
          short8 pf = frag4(w0, w1, w2, w3);
          int colb2 = jj * 64 + ks2 * 32 + hi * 16;
          short8 vf0 = *(const short8*)(stage + vbase + l31 * 256 + (colb2 ^ (l15 << 4)));
          accO0 = __builtin_amdgcn_mfma_f32_32x32x16_bf16(vf0, pf, accO0, 0, 0, 0);
          short8 vf1 = *(const short8*)(stage + vbase + l31 * 256 + ((128 + colb2) ^ (l15 << 4)));
          accO1 = __builtin_amdgcn_mfma_f32_32x32x16_bf16(vf1, pf, accO1, 0, 0, 0);
          accL = __builtin_amdgcn_mfma_f32_32x32x16_bf16(ones, pf, accL, 0, 0, 0);
        }
      }
      __builtin_amdgcn_s_setprio(0);
      lsum += accL[0];
    }
  }

  __syncthreads();
  if (half == 1) {
#pragma unroll
    for (int dd = 0; dd < 2; dd++) {
      const f32x16& a = dd ? accO1 : accO0;
#pragma unroll
      for (int rg = 0; rg < 16; rg++) {
        int d = dd * 32 + 8 * (rg >> 2) + 4 * hi + (rg & 3);
        Obuf[(hh * 64 + d) * 32 + l31] = a[rg];
      }
    }
    if (!hi) { ml[(hh * 2 + 0) * 32 + l31] = m; ml[(hh * 2 + 1) * 32 + l31] = lsum; }
  }
  __syncthreads();
  if (half == 0) {
    float m1 = ml[(hh * 2 + 0) * 32 + l31];
    float l1 = ml[(hh * 2 + 1) * 32 + l31];
    float ms = fmaxf(m, m1);
    float a0 = exp2f(m - ms), a1 = exp2f(m1 - ms);
    float inv = 1.0f / (lsum * a0 + l1 * a1);
    a0 *= inv; a1 *= inv;
#pragma unroll
    for (int dd = 0; dd < 2; dd++) {
      const f32x16& a = dd ? accO1 : accO0;
#pragma unroll
      for (int b = 0; b < 4; b++) {
        float o[4];
#pragma unroll
        for (int e = 0; e < 4; e++) {
          int d = dd * 32 + 8 * b + 4 * hi + e;
          o[e] = a[4 * b + e] * a0 + Obuf[(hh * 64 + d) * 32 + l31] * a1;
        }
        union { unsigned uu[2]; ushort4 v; } ov;
        ov.uu[0] = pk2bf(o[0], o[1]);
        ov.uu[1] = pk2bf(o[2], o[3]);
        *(ushort4*)(Yb + (size_t)qrow * 1024 + h * 64 + dd * 32 + b * 8 + hi * 4) = ov.v;
      }
    }
  }
}

extern "C" void kernel_launch(void* const* d_in, const int* in_sizes, int n_in,
                              void* d_out, int out_size, void* d_ws, size_t ws_size,
                              hipStream_t stream) {
  const float* x = (const float*)d_in[0];
  const float* wq = (const float*)d_in[1];
  const float* wk = (const float*)d_in[2];
  const float* wv = (const float*)d_in[3];
  const float* wo = (const float*)d_in[4];
  const float* qw = (const float*)d_in[5];
  const float* kw = (const float*)d_in[6];
  const float* fc = (const float*)d_in[7];
  const float* fs = (const float*)d_in[8];
  float* out = (float*)d_out;

  char* p = (char*)d_ws;
  auto alloc = [&](size_t b) {
    char* q = p;
    p += (b + 255) & ~(size_t)255;
    return q;
  };
  unsigned short* xb = (unsigned short*)alloc((size_t)4096 * 1024 * 2);
  unsigned short* wqkvb = (unsigned short*)alloc((size_t)1536 * 1024 * 2);
  unsigned short* wob = (unsigned short*)alloc((size_t)1024 * 1024 * 2);
  unsigned short* Qb = (unsigned short*)alloc((size_t)4096 * 1024 * 2);
  unsigned short* Kb = (unsigned short*)alloc((size_t)4096 * 256 * 2);
  unsigned short* Vtg = (unsigned short*)alloc((size_t)256 * 4096 * 2);
  unsigned short* Yb = (unsigned short*)alloc((size_t)4096 * 1024 * 2);

  k_f2b_all<<<6656, 256, 0, stream>>>(x, wq, wk, wv, wo, xb, wqkvb, wob);
  k_gemm_qkv<<<768, 256, 0, stream>>>(xb, wqkvb, qw, kw, fc, fs, Qb, Kb, Vtg);
  k_attn9<<<512, 512, 0, stream>>>(Qb, Kb, Vtg, Yb);
  k_gemm_out<<<512, 256, 0, stream>>>(Yb, wob, out);
}

// Round 18
// 107.849 us; speedup vs baseline: 1.3494x; 1.0078x over previous
//
#include <hip/hip_runtime.h>
#include <hip/hip_bf16.h>

// RotarySelfAttention: B=1 T=4096 C=1024 NH=16 NKV=4 HD=64 WIN=1024
// R15 pipeline; attn LDS padded to 56KB to cap at 2 blocks/CU and force the
// 512 attn blocks to spread across all 256 CUs (packing-hypothesis probe).

#define WIN_SZ 1024

typedef __attribute__((ext_vector_type(8))) short short8;
typedef __attribute__((ext_vector_type(8))) unsigned short ushort8;
typedef __attribute__((ext_vector_type(4))) float f32x4;
typedef __attribute__((ext_vector_type(16))) float f32x16;

#define GLOAD_LDS16(g, s)                                              \
  __builtin_amdgcn_global_load_lds(                                    \
      (const __attribute__((address_space(1))) unsigned int*)(g),      \
      (__attribute__((address_space(3))) unsigned int*)(s), 16, 0, 0)

__device__ __forceinline__ unsigned short f2bf(float f) {
  union { float f; unsigned u; } v; v.f = f;
  unsigned r = v.u + 0x7fffu + ((v.u >> 16) & 1u);
  return (unsigned short)(r >> 16);
}

__device__ __forceinline__ unsigned pk2bf(float lo, float hi) {
  __hip_bfloat162 h = __float22bfloat162_rn(make_float2(lo, hi));
  union { __hip_bfloat162 h; unsigned u; } c; c.h = h; return c.u;
}

__device__ __forceinline__ short8 frag4(unsigned w0, unsigned w1, unsigned w2, unsigned w3) {
  union { unsigned u[4]; short8 s; } x;
  x.u[0] = w0; x.u[1] = w1; x.u[2] = w2; x.u[3] = w3; return x.s;
}

// ---------------- fused fp32 -> bf16 convert for x, wq, wk, wv, wo ----------------
__global__ __launch_bounds__(256) void k_f2b_all(const float* __restrict__ x,
                                                 const float* __restrict__ wq,
                                                 const float* __restrict__ wk,
                                                 const float* __restrict__ wv,
                                                 const float* __restrict__ wo,
                                                 unsigned short* __restrict__ xb,
                                                 unsigned short* __restrict__ wqkvb,
                                                 unsigned short* __restrict__ wob) {
  int q = blockIdx.x * 256 + threadIdx.x;
  const float* src;
  unsigned short* dst;
  int off;
  if (q < 1048576) { src = x; dst = xb; off = q; }
  else if (q < 1310720) { src = wq; dst = wqkvb; off = q - 1048576; }
  else if (q < 1376256) { src = wk; dst = wqkvb + 1024 * 1024; off = q - 1310720; }
  else if (q < 1441792) { src = wv; dst = wqkvb + 1280 * 1024; off = q - 1376256; }
  else { src = wo; dst = wob; off = q - 1441792; }
  float4 v = ((const float4*)src)[off];
  ushort4 o;
  o.x = f2bf(v.x); o.y = f2bf(v.y); o.z = f2bf(v.z); o.w = f2bf(v.w);
  ((ushort4*)dst)[off] = o;
}

// ---------------- QKV GEMM + fused RMSNorm/RoPE epilogue ----------------
__global__ __launch_bounds__(256) void k_gemm_qkv(const unsigned short* __restrict__ A,
                                                  const unsigned short* __restrict__ B,
                                                  const float* __restrict__ qw,
                                                  const float* __restrict__ kw,
                                                  const float* __restrict__ fc,
                                                  const float* __restrict__ fs,
                                                  unsigned short* __restrict__ Qb,
                                                  unsigned short* __restrict__ Kb,
                                                  unsigned short* __restrict__ Vtg) {
  const int K = 1024;
  __shared__ unsigned short As[2][128 * 64];
  __shared__ unsigned short Bs[2][64 * 64];
  const int id = blockIdx.x;
  const int chunk = gridDim.x >> 3;
  const int swz = (id & 7) * chunk + (id >> 3);
  const int n_idx = swz % 24, m_idx = swz / 24;
  const int m0 = m_idx * 128, n0 = n_idx * 64;

  const int tid = threadIdx.x;
  const int w = tid >> 6, l = tid & 63;
  const int wr = w >> 1, wc = w & 1;
  const int r = l & 15, g = l >> 4;
  const int lr = l >> 3, lc = l & 7;
  const int srowb = w * 32, browb = w * 16;

  f32x4 acc[4][2];
#pragma unroll
  for (int i = 0; i < 4; i++)
#pragma unroll
    for (int j = 0; j < 2; j++) acc[i][j] = {0.f, 0.f, 0.f, 0.f};

  const unsigned short* Ag = A + (size_t)(m0 + srowb + lr) * K + lc * 8;
  const unsigned short* Bg = B + (size_t)(n0 + browb + lr) * K + lc * 8;

  auto stage = [&](int buf, int k0) {
#pragma unroll
    for (int it = 0; it < 4; it++)
      GLOAD_LDS16(Ag + (size_t)(it * 8) * K + k0, &As[buf][(srowb + it * 8) * 64]);
#pragma unroll
    for (int it = 0; it < 2; it++)
      GLOAD_LDS16(Bg + (size_t)(it * 8) * K + k0, &Bs[buf][(browb + it * 8) * 64]);
  };

  stage(0, 0);
  __syncthreads();
  int cur = 0;
  const int NT = K >> 6;
  for (int t = 0; t < NT; ++t) {
    if (t + 1 < NT) stage(cur ^ 1, (t + 1) << 6);
    const char* Ab = (const char*)As[cur];
    const char* Bb = (const char*)Bs[cur];
#pragma unroll
    for (int kk = 0; kk < 2; kk++) {
      short8 af[4], bfr[2];
#pragma unroll
      for (int mi = 0; mi < 4; mi++)
        af[mi] = *(const short8*)(Ab + (wr * 64 + mi * 16 + r) * 128 + kk * 64 + g * 16);
#pragma unroll
      for (int nj = 0; nj < 2; nj++)
        bfr[nj] = *(const short8*)(Bb + (wc * 32 + nj * 16 + r) * 128 + kk * 64 + g * 16);
#pragma unroll
      for (int mi = 0; mi < 4; mi++)
#pragma unroll
        for (int nj = 0; nj < 2; nj++)
          acc[mi][nj] = __builtin_amdgcn_mfma_f32_16x16x32_bf16(af[mi], bfr[nj], acc[mi][nj], 0, 0, 0);
    }
    __syncthreads();
    cur ^= 1;
  }

  const int u = n0 >> 6;
  if (u < 20) {
    float* ssb = (float*)As;  // [128][2]
    f32x4 sv[4];
#pragma unroll
    for (int mi = 0; mi < 4; mi++) {
      f32x4 s;
#pragma unroll
      for (int e = 0; e < 4; e++)
        s[e] = acc[mi][0][e] * acc[mi][0][e] + acc[mi][1][e] * acc[mi][1][e];
#pragma unroll
      for (int off = 1; off < 16; off <<= 1)
#pragma unroll
        for (int e = 0; e < 4; e++) s[e] += __shfl_xor(s[e], off);
      sv[mi] = s;
    }
    if (r == 0) {
#pragma unroll
      for (int mi = 0; mi < 4; mi++)
#pragma unroll
        for (int e = 0; e < 4; e++)
          ssb[(wr * 64 + mi * 16 + g * 4 + e) * 2 + wc] = sv[mi][e];
    }
    __syncthreads();
    const float escale = (u < 16) ? 0.1803368801111204f : 1.0f;
    const float* wgt = (u < 16) ? qw : kw;
#pragma unroll
    for (int mi = 0; mi < 4; mi++) {
      const int rl0 = wr * 64 + mi * 16 + g * 4;
      const int row0 = m0 + rl0;
#pragma unroll
      for (int e = 0; e < 4; e++) {
        const int row = row0 + e;
        float ss = ssb[(rl0 + e) * 2] + ssb[(rl0 + e) * 2 + 1];
        float rms = rsqrtf(ss * (1.0f / 64.0f) + 1e-5f);
#pragma unroll
        for (int nj = 0; nj < 2; nj++) {
          const int cl = wc * 32 + nj * 16 + r;
          float vn = acc[mi][nj][e] * rms * wgt[cl];
          float c = fc[row * 32 + (cl >> 1)];
          float s = fs[row * 32 + (cl >> 1)];
          float pvn = __shfl_xor(vn, 1);
          float outv = (cl & 1) ? (pvn * s + vn * c) : (vn * c - pvn * s);
          unsigned short ob = f2bf(outv * escale);
          if (u < 16) Qb[(size_t)row * 1024 + n0 + cl] = ob;
          else Kb[(size_t)row * 256 + (n0 - 1024) + cl] = ob;
        }
      }
    }
  } else {
#pragma unroll
    for (int mi = 0; mi < 4; mi++) {
      const int row0 = m0 + wr * 64 + mi * 16 + g * 4;
#pragma unroll
      for (int nj = 0; nj < 2; nj++) {
        const int d = (n0 - 1280) + wc * 32 + nj * 16 + r;
        ushort4 ov;
        ov.x = f2bf(acc[mi][nj][0]);
        ov.y = f2bf(acc[mi][nj][1]);
        ov.z = f2bf(acc[mi][nj][2]);
        ov.w = f2bf(acc[mi][nj][3]);
        *(ushort4*)(Vtg + (size_t)d * 4096 + row0) = ov;
      }
    }
  }
}

// ---------------- out GEMM: 128x64 dbuf, f32 out ----------------
__global__ __launch_bounds__(256) void k_gemm_out(const unsigned short* __restrict__ A,
                                                  const unsigned short* __restrict__ B,
                                                  float* __restrict__ C) {
  const int K = 1024, N = 1024;
  __shared__ unsigned short As[2][128 * 64];
  __shared__ unsigned short Bs[2][64 * 64];
  const int id = blockIdx.x;
  const int chunk = gridDim.x >> 3;
  const int swz = (id & 7) * chunk + (id >> 3);
  const int n_idx = swz % 16, m_idx = swz / 16;
  const int m0 = m_idx * 128, n0 = n_idx * 64;

  const int tid = threadIdx.x;
  const int w = tid >> 6, l = tid & 63;
  const int wr = w >> 1, wc = w & 1;
  const int r = l & 15, g = l >> 4;
  const int lr = l >> 3, lc = l & 7;
  const int srowb = w * 32, browb = w * 16;

  f32x4 acc[4][2];
#pragma unroll
  for (int i = 0; i < 4; i++)
#pragma unroll
    for (int j = 0; j < 2; j++) acc[i][j] = {0.f, 0.f, 0.f, 0.f};

  const unsigned short* Ag = A + (size_t)(m0 + srowb + lr) * K + lc * 8;
  const unsigned short* Bg = B + (size_t)(n0 + browb + lr) * K + lc * 8;

  auto stage = [&](int buf, int k0) {
#pragma unroll
    for (int it = 0; it < 4; it++)
      GLOAD_LDS16(Ag + (size_t)(it * 8) * K + k0, &As[buf][(srowb + it * 8) * 64]);
#pragma unroll
    for (int it = 0; it < 2; it++)
      GLOAD_LDS16(Bg + (size_t)(it * 8) * K + k0, &Bs[buf][(browb + it * 8) * 64]);
  };

  stage(0, 0);
  __syncthreads();
  int cur = 0;
  const int NT = K >> 6;
  for (int t = 0; t < NT; ++t) {
    if (t + 1 < NT) stage(cur ^ 1, (t + 1) << 6);
    const char* Ab = (const char*)As[cur];
    const char* Bb = (const char*)Bs[cur];
#pragma unroll
    for (int kk = 0; kk < 2; kk++) {
      short8 af[4], bfr[2];
#pragma unroll
      for (int mi = 0; mi < 4; mi++)
        af[mi] = *(const short8*)(Ab + (wr * 64 + mi * 16 + r) * 128 + kk * 64 + g * 16);
#pragma unroll
      for (int nj = 0; nj < 2; nj++)
        bfr[nj] = *(const short8*)(Bb + (wc * 32 + nj * 16 + r) * 128 + kk * 64 + g * 16);
#pragma unroll
      for (int mi = 0; mi < 4; mi++)
#pragma unroll
        for (int nj = 0; nj < 2; nj++)
          acc[mi][nj] = __builtin_amdgcn_mfma_f32_16x16x32_bf16(af[mi], bfr[nj], acc[mi][nj], 0, 0, 0);
    }
    __syncthreads();
    cur ^= 1;
  }

#pragma unroll
  for (int mi = 0; mi < 4; mi++)
#pragma unroll
    for (int nj = 0; nj < 2; nj++) {
      int row = m0 + wr * 64 + mi * 16 + g * 4;
      int col = n0 + wc * 32 + nj * 16 + r;
#pragma unroll
      for (int e = 0; e < 4; e++)
        C[(size_t)(row + e) * N + col] = acc[mi][nj][e];
    }
}

// ---------------- flash attention: R8 structure + MFMA row-sum; LDS padded ----------------
// LDS padded to 56KB so max 2 blocks/CU -> the 512 blocks must spread across all
// 256 CUs (defeats potential 4-deep packing that idles CUs).
__global__ __launch_bounds__(512, 4) void k_attn9(const unsigned short* __restrict__ Qb,
                                                  const unsigned short* __restrict__ Kb,
                                                  const unsigned short* __restrict__ Vtg,
                                                  unsigned short* __restrict__ Yb) {
  __shared__ char smem[57344];  // 33KB used + pad -> caps at 2 blocks/CU
  char* stage = smem;
  float* Obuf = (float*)smem;
  float* ml = (float*)(smem + 32768);

  const int id = blockIdx.x;
  const int cupair = id & 255, sel = id >> 8;
  int qi = cupair >> 1;
  if (sel) qi = 127 - qi;
  const int hk = (cupair & 1) * 2 + sel;
  const int q0 = qi * 32;

  const int tid = threadIdx.x, w = tid >> 6, l = tid & 63;
  const int hh = w & 3, half = w >> 2;
  const int h = hk * 4 + hh;
  const int l31 = l & 31, hi = l >> 5, l15 = l & 15;
  const int qrow = q0 + l31;

  int jlo = q0 - (WIN_SZ - 1);
  if (jlo < 0) jlo = 0;
  jlo &= ~63;
  const int jlast = ((q0 + 31) >> 6) << 6;
  const int nt = ((jlast - jlo) >> 6) + 1;
  const int nh0 = (nt + 1) >> 1;

  const int sb = tid >> 7;
  const int su = tid & 127;
  const int srow = su >> 1;
  const int sg = (su & 1) * 4;
  const int sbase = sb * 8192 + (srow & 31) * 256;
  const int srx = (srow & 15) << 4;
  const int srh = (srow >> 5) * 128;
  const bool isV = sb & 1;
  const unsigned short* gK = Kb + (size_t)srow * 256 + hk * 64 + sg * 8;
  const unsigned short* gV = Vtg + (size_t)(hk * 64 + srow) * 4096 + sg * 8;

  short8 qf[4];
#pragma unroll
  for (int ks = 0; ks < 4; ks++)
    qf[ks] = *(const short8*)(Qb + (size_t)qrow * 1024 + h * 64 + ks * 16 + hi * 8);

  const short8 ones = frag4(0x3F803F80u, 0x3F803F80u, 0x3F803F80u, 0x3F803F80u);

  f32x16 accO0, accO1;
#pragma unroll
  for (int i = 0; i < 16; i++) { accO0[i] = 0.f; accO1[i] = 0.f; }
  float m = -1e30f, lsum = 0.f;

  ushort8 pre[4];
  auto prefetch = [&](int s) {
    int jt0 = jlo + (s << 6);
    int t1 = nh0 + s;
    int jt1 = (t1 < nt) ? (jlo + (t1 << 6)) : jlo;
    int jt = (sb >= 2) ? jt1 : jt0;
    if (!isV) {
      const unsigned short* g = gK + (size_t)jt * 256;
#pragma unroll
      for (int e = 0; e < 4; e++) pre[e] = *(const ushort8*)(g + e * 8);
    } else {
      const unsigned short* g = gV + jt;
#pragma unroll
      for (int e = 0; e < 4; e++) pre[e] = *(const ushort8*)(g + e * 8);
    }
  };
  prefetch(0);

  const int kbase = half * 16384;
  const int vbase = kbase + 8192;

  for (int s = 0; s < nh0; ++s) {
    __syncthreads();
#pragma unroll
    for (int e = 0; e < 4; e++) {
      int dst = sbase + ((srh + (sg + e) * 16) ^ srx);
      *(ushort8*)(stage + dst) = pre[e];
    }
    __syncthreads();
    if (s + 1 < nh0) prefetch(s + 1);

    const int myt = half ? (nh0 + s) : s;
    if (myt < nt) {
      const int jt = jlo + (myt << 6);

      f32x16 st0, st1;
#pragma unroll
      for (int i = 0; i < 16; i++) { st0[i] = 0.f; st1[i] = 0.f; }
      __builtin_amdgcn_s_setprio(1);
#pragma unroll
      for (int ks = 0; ks < 4; ks++) {
        int colb = ks * 32 + hi * 16;
        short8 kf0 = *(const short8*)(stage + kbase + l31 * 256 + (colb ^ (l15 << 4)));
        st0 = __builtin_amdgcn_mfma_f32_32x32x16_bf16(kf0, qf[ks], st0, 0, 0, 0);
        short8 kf1 = *(const short8*)(stage + kbase + l31 * 256 + ((128 + colb) ^ (l15 << 4)));
        st1 = __builtin_amdgcn_mfma_f32_32x32x16_bf16(kf1, qf[ks], st1, 0, 0, 0);
      }
      __builtin_amdgcn_s_setprio(0);

      if (jt + 63 > q0 || (q0 + 31) - jt >= WIN_SZ) {
        const int jb = jt + hi * 4;
#pragma unroll
        for (int rg = 0; rg < 16; rg++) {
          int j0 = jb + (rg & 3) + 8 * (rg >> 2);
          if (!((j0 <= qrow) && (qrow - j0 < WIN_SZ))) st0[rg] = -3.0e38f;
          int j1 = j0 + 32;
          if (!((j1 <= qrow) && (qrow - j1 < WIN_SZ))) st1[rg] = -3.0e38f;
        }
      }

      float mx = st0[0];
#pragma unroll
      for (int rg = 1; rg < 16; rg++) mx = fmaxf(mx, st0[rg]);
#pragma unroll
      for (int rg = 0; rg < 16; rg++) mx = fmaxf(mx, st1[rg]);
      mx = fmaxf(mx, __shfl_xor(mx, 32));
      if (!__all(mx <= m + 8.0f)) {
        float mnew = fmaxf(m, mx);
        float alpha = exp2f(m - mnew);
#pragma unroll
        for (int rg = 0; rg < 16; rg++) { accO0[rg] *= alpha; accO1[rg] *= alpha; }
        lsum *= alpha;
        m = mnew;
      }
#pragma unroll
      for (int rg = 0; rg < 16; rg++) st0[rg] = exp2f(st0[rg] - m);
#pragma unroll
      for (int rg = 0; rg < 16; rg++) st1[rg] = exp2f(st1[rg] - m);

      unsigned pd0[2][4], pd1[2][4];
#pragma unroll
      for (int b = 0; b < 4; b++) {
        pd0[0][b] = pk2bf(st0[4 * b], st0[4 * b + 1]);
        pd1[0][b] = pk2bf(st0[4 * b + 2], st0[4 * b + 3]);
        pd0[1][b] = pk2bf(st1[4 * b], st1[4 * b + 1]);
        pd1[1][b] = pk2bf(st1[4 * b + 2], st1[4 * b + 3]);
      }

      f32x16 accL;
#pragma unroll
      for (int i = 0; i < 16; i++) accL[i] = 0.f;

      __builtin_amdgcn_s_setprio(1);
#pragma unroll
      for (int jj = 0; jj < 2; jj++) {
#pragma unroll
        for (int ks2 = 0; ks2 < 2; ks2++) {
          unsigned a0 = pd0[jj][2 * ks2], a1 = pd0[jj][2 * ks2 + 1];
          unsigned b0 = pd1[jj][2 * ks2], b1 = pd1[jj][2 * ks2 + 1];
          unsigned a0x = __shfl_xor(a0, 32), a1x = __shfl_xor(a1, 32);
          unsigned b0x = __shfl_xor(b0, 32), b1x = __shfl_xor(b1, 32);
          unsigned w0 = hi ? a1x : a0;
          unsigned w1 = hi ? b1x : b0;
          unsigned w2 = hi ? a1 : a0x;
          unsigned w3 = hi ? b1 : b0x;
          short8 pf = frag4(w0, w1, w2, w3);
          int colb2 = jj * 64 + ks2 * 32 + hi * 16;
          short8 vf0 = *(const short8*)(stage + vbase + l31 * 256 + (colb2 ^ (l15 << 4)));
          accO0 = __builtin_amdgcn_mfma_f32_32x32x16_bf16(vf0, pf, accO0, 0, 0, 0);
          short8 vf1 = *(const short8*)(stage + vbase + l31 * 256 + ((128 + colb2) ^ (l15 << 4)));
          accO1 = __builtin_amdgcn_mfma_f32_32x32x16_bf16(vf1, pf, accO1, 0, 0, 0);
          accL = __builtin_amdgcn_mfma_f32_32x32x16_bf16(ones, pf, accL, 0, 0, 0);
        }
      }
      __builtin_amdgcn_s_setprio(0);
      lsum += accL[0];
    }
  }

  __syncthreads();
  if (half == 1) {
#pragma unroll
    for (int dd = 0; dd < 2; dd++) {
      const f32x16& a = dd ? accO1 : accO0;
#pragma unroll
      for (int rg = 0; rg < 16; rg++) {
        int d = dd * 32 + 8 * (rg >> 2) + 4 * hi + (rg & 3);
        Obuf[(hh * 64 + d) * 32 + l31] = a[rg];
      }
    }
    if (!hi) { ml[(hh * 2 + 0) * 32 + l31] = m; ml[(hh * 2 + 1) * 32 + l31] = lsum; }
  }
  __syncthreads();
  if (half == 0) {
    float m1 = ml[(hh * 2 + 0) * 32 + l31];
    float l1 = ml[(hh * 2 + 1) * 32 + l31];
    float ms = fmaxf(m, m1);
    float a0 = exp2f(m - ms), a1 = exp2f(m1 - ms);
    float inv = 1.0f / (lsum * a0 + l1 * a1);
    a0 *= inv; a1 *= inv;
#pragma unroll
    for (int dd = 0; dd < 2; dd++) {
      const f32x16& a = dd ? accO1 : accO0;
#pragma unroll
      for (int b = 0; b < 4; b++) {
        float o[4];
#pragma unroll
        for (int e = 0; e < 4; e++) {
          int d = dd * 32 + 8 * b + 4 * hi + e;
          o[e] = a[4 * b + e] * a0 + Obuf[(hh * 64 + d) * 32 + l31] * a1;
        }
        union { unsigned uu[2]; ushort4 v; } ov;
        ov.uu[0] = pk2bf(o[0], o[1]);
        ov.uu[1] = pk2bf(o[2], o[3]);
        *(ushort4*)(Yb + (size_t)qrow * 1024 + h * 64 + dd * 32 + b * 8 + hi * 4) = ov.v;
      }
    }
  }
}

extern "C" void kernel_launch(void* const* d_in, const int* in_sizes, int n_in,
                              void* d_out, int out_size, void* d_ws, size_t ws_size,
                              hipStream_t stream) {
  const float* x = (const float*)d_in[0];
  const float* wq = (const float*)d_in[1];
  const float* wk = (const float*)d_in[2];
  const float* wv = (const float*)d_in[3];
  const float* wo = (const float*)d_in[4];
  const float* qw = (const float*)d_in[5];
  const float* kw = (const float*)d_in[6];
  const float* fc = (const float*)d_in[7];
  const float* fs = (const float*)d_in[8];
  float* out = (float*)d_out;

  char* p = (char*)d_ws;
  auto alloc = [&](size_t b) {
    char* q = p;
    p += (b + 255) & ~(size_t)255;
    return q;
  };
  unsigned short* xb = (unsigned short*)alloc((size_t)4096 * 1024 * 2);
  unsigned short* wqkvb = (unsigned short*)alloc((size_t)1536 * 1024 * 2);
  unsigned short* wob = (unsigned short*)alloc((size_t)1024 * 1024 * 2);
  unsigned short* Qb = (unsigned short*)alloc((size_t)4096 * 1024 * 2);
  unsigned short* Kb = (unsigned short*)alloc((size_t)4096 * 256 * 2);
  unsigned short* Vtg = (unsigned short*)alloc((size_t)256 * 4096 * 2);
  unsigned short* Yb = (unsigned short*)alloc((size_t)4096 * 1024 * 2);

  k_f2b_all<<<6656, 256, 0, stream>>>(x, wq, wk, wv, wo, xb, wqkvb, wob);
  k_gemm_qkv<<<768, 256, 0, stream>>>(xb, wqkvb, qw, kw, fc, fs, Qb, Kb, Vtg);
  k_attn9<<<512, 512, 0, stream>>>(Qb, Kb, Vtg, Yb);
  k_gemm_out<<<512, 256, 0, stream>>>(Yb, wob, out);
}